// Round 15
// baseline (4793.964 us; speedup 1.0000x reference)
//
#include <hip/hip_runtime.h>

#define SEQ_LEN 256
#define SPIKE_STEPS 7
#define BATCH 128
#define IN_DIM 96
#define HIDDEN 512
#define OUT_DIM 2

// d_ws layout (f32 weights): W0T [96*512] | W1T [512*512] | W2T [512*512]
#define W0T_OFF 0
#define W1T_OFF (IN_DIM * HIDDEN)
#define W2T_OFF (W1T_OFF + HIDDEN * HIDDEN)

typedef float f32x4 __attribute__((ext_vector_type(4)));
typedef float f32x2 __attribute__((ext_vector_type(2)));

__global__ void transpose_kernel(const float* __restrict__ in, float* __restrict__ out,
                                 int rows, int cols) {
    int idx = blockIdx.x * blockDim.x + threadIdx.x;
    if (idx < rows * cols) {
        int r = idx / cols, c = idx - r * cols;
        out[c * rows + r] = in[idx];
    }
}

// Packed f32 fma: acc.{lo,hi} += w * m.{lo,hi}. Lowers to v_pk_fma_f32
// (VOP3P) on gfx950 (proven R5/R7). Each half is an independent IEEE RN fma
// => bit-identical to two scalar __fmaf_rn. The two halves belong to
// DIFFERENT steps' accumulator chains => no reordering within any step.
__device__ __forceinline__ void pkfma(f32x2& acc, float w, f32x2 m) {
    const f32x2 wv = {w, w};
    acc = __builtin_elementwise_fma(wv, m, acc);
}

// TWO-COLUMN union-batched 7-step row sum (R13's exact, measured-best form:
// plain dword weight loads, depth-1 pipeline, rank-indexed masks).
// Numerics: per column, per step s, union rows visited in ascending rank
// order; active rows add fma(1,w,acc)=RN(acc+w); inactive rows add
// fma(0,w,acc)=acc exactly (acc never -0: starts +0, +0 + +/-0 = +0 in RN).
// Pads are (row 0, mask 0). => per-column sums bit-identical to R1/R3/R7.
__device__ __forceinline__ void union_sum7_2(const float* __restrict__ W,
                                             const int* __restrict__ act,
                                             const float (* __restrict__ fmp)[8],
                                             int npad, int tid,
                                             f32x2* __restrict__ accA,
                                             f32x2* __restrict__ accB) {
    if (npad <= 0) return;
    const float* WtA = W + tid;
    const float* WtB = W + tid + 256;
    int rows[16];
    float wcA[16], wcB[16];
    {
        const int4* av = reinterpret_cast<const int4*>(act);
        int4 a0 = av[0], a1 = av[1], a2 = av[2], a3 = av[3];
        rows[0]=a0.x; rows[1]=a0.y; rows[2]=a0.z; rows[3]=a0.w;
        rows[4]=a1.x; rows[5]=a1.y; rows[6]=a1.z; rows[7]=a1.w;
        rows[8]=a2.x; rows[9]=a2.y; rows[10]=a2.z; rows[11]=a2.w;
        rows[12]=a3.x; rows[13]=a3.y; rows[14]=a3.z; rows[15]=a3.w;
    }
    #pragma unroll
    for (int k = 0; k < 16; ++k) {
        wcA[k] = WtA[rows[k] * HIDDEN];
        wcB[k] = WtB[rows[k] * HIDDEN];
    }

    for (int n = 16; n < npad; n += 16) {
        int nrows[16];
        float wnA[16], wnB[16];
        {
            const int4* av = reinterpret_cast<const int4*>(act + n);
            int4 a0 = av[0], a1 = av[1], a2 = av[2], a3 = av[3];
            nrows[0]=a0.x; nrows[1]=a0.y; nrows[2]=a0.z; nrows[3]=a0.w;
            nrows[4]=a1.x; nrows[5]=a1.y; nrows[6]=a1.z; nrows[7]=a1.w;
            nrows[8]=a2.x; nrows[9]=a2.y; nrows[10]=a2.z; nrows[11]=a2.w;
            nrows[12]=a3.x; nrows[13]=a3.y; nrows[14]=a3.z; nrows[15]=a3.w;
        }
        #pragma unroll
        for (int k = 0; k < 16; ++k) {
            wnA[k] = WtA[nrows[k] * HIDDEN];
            wnB[k] = WtB[nrows[k] * HIDDEN];
        }

        const int base = n - 16;
        #pragma unroll
        for (int k = 0; k < 16; ++k) {
            f32x4 fa = *reinterpret_cast<const f32x4*>(&fmp[base + k][0]);
            f32x4 fb = *reinterpret_cast<const f32x4*>(&fmp[base + k][4]);
            f32x2 m01 = __builtin_shufflevector(fa, fa, 0, 1);
            f32x2 m23 = __builtin_shufflevector(fa, fa, 2, 3);
            f32x2 m45 = __builtin_shufflevector(fb, fb, 0, 1);
            f32x2 m67 = __builtin_shufflevector(fb, fb, 2, 3);
            pkfma(accA[0], wcA[k], m01);
            pkfma(accA[1], wcA[k], m23);
            pkfma(accA[2], wcA[k], m45);
            pkfma(accA[3], wcA[k], m67);
            pkfma(accB[0], wcB[k], m01);
            pkfma(accB[1], wcB[k], m23);
            pkfma(accB[2], wcB[k], m45);
            pkfma(accB[3], wcB[k], m67);
        }
        #pragma unroll
        for (int k = 0; k < 16; ++k) { wcA[k] = wnA[k]; wcB[k] = wnB[k]; }
    }
    const int base = npad - 16;
    #pragma unroll
    for (int k = 0; k < 16; ++k) {
        f32x4 fa = *reinterpret_cast<const f32x4*>(&fmp[base + k][0]);
        f32x4 fb = *reinterpret_cast<const f32x4*>(&fmp[base + k][4]);
        f32x2 m01 = __builtin_shufflevector(fa, fa, 0, 1);
        f32x2 m23 = __builtin_shufflevector(fa, fa, 2, 3);
        f32x2 m45 = __builtin_shufflevector(fb, fb, 0, 1);
        f32x2 m67 = __builtin_shufflevector(fb, fb, 2, 3);
        pkfma(accA[0], wcA[k], m01);
        pkfma(accA[1], wcA[k], m23);
        pkfma(accA[2], wcA[k], m45);
        pkfma(accA[3], wcA[k], m67);
        pkfma(accB[0], wcB[k], m01);
        pkfma(accB[1], wcB[k], m23);
        pkfma(accB[2], wcB[k], m45);
        pkfma(accB[3], wcB[k], m67);
    }
}

// Build the union active list (ascending neuron order) + rank-indexed
// per-row step-mask floats. Full 512-thread phase (unchanged from R7).
__device__ __forceinline__ int build_union(const unsigned long long (*zm7)[8],
                                           int* act, float (*fmp)[8],
                                           int wid, int lane, int tid, int m7) {
    unsigned long long um[8];
    #pragma unroll
    for (int q = 0; q < 8; ++q) {
        unsigned long long u = zm7[0][q];
        #pragma unroll
        for (int s = 1; s < SPIKE_STEPS; ++s) u |= zm7[s][q];
        um[q] = u;
    }
    int pre = 0, total = 0;
    #pragma unroll
    for (int q = 0; q < 8; ++q) {
        int p = __popcll(um[q]);
        total += p;
        if (q < wid) pre += p;
    }
    if (m7 != 0) {
        int rank = pre + __popcll(um[wid] & ((1ull << lane) - 1ull));
        act[rank] = tid;
        f32x4 v0, v4;
        #pragma unroll
        for (int s = 0; s < 4; ++s) v0[s] = ((m7 >> s) & 1) ? 1.0f : 0.0f;
        #pragma unroll
        for (int s = 0; s < 3; ++s) v4[s] = ((m7 >> (4 + s)) & 1) ? 1.0f : 0.0f;
        v4[3] = 0.f;
        *reinterpret_cast<f32x4*>(&fmp[rank][0]) = v0;
        *reinterpret_cast<f32x4*>(&fmp[rank][4]) = v4;
    }
    int npad = (total + 15) & ~15;
    if (tid < npad - total) {
        act[total + tid] = 0;                          // row 0, mask 0 pad
        const f32x4 z = {0.f, 0.f, 0.f, 0.f};
        *reinterpret_cast<f32x4*>(&fmp[total + tid][0]) = z;
        *reinterpret_cast<f32x4*>(&fmp[total + tid][4]) = z;
    }
    return npad;
}

// FUSED single-block kernel: one 512-thread block per batch element runs
// ALL THREE layers sequentially per seq step. Rationale: R7-R14 pinned the
// per-seq-step time at ~27k cyc while every resource-targeted change
// (L2 bytes, LDS readers, SALU, prefetch depth, VMEM instr count) was null
// => the floor is the producer->consumer handoff (agent-scope L3 stores,
// vmcnt drain, cross-XCD visibility, spin-poll) + cross-block coupling.
// Fusing removes ALL of it: the z1 masks pass through LDS (ballot ->
// zm7 in-place), 5 in-block barriers per step, no zbuf/ctr/spin.
// All compute components are byte-for-byte R13's => bit-identical output
// (absmax must be exactly 0.25).
__launch_bounds__(512, 1)
__global__ void snn_fused_kernel(const float* __restrict__ x,     // [256,128,96]
                                 const float* __restrict__ Wout,  // [2,512]
                                 const float* __restrict__ betas, // [3]
                                 const float* __restrict__ thrs,  // [3]
                                 const float* __restrict__ W0T,   // [96,512]
                                 const float* __restrict__ W1T,   // [512,512]
                                 const float* __restrict__ W2T,   // [512,512]
                                 float* __restrict__ out)         // [256,128,2]
{
    const int b    = blockIdx.x;
    const int tid  = threadIdx.x;
    const int lane = tid & 63;
    const int wid  = tid >> 6;
    const bool mv  = (tid < 256);       // matvec-active threads (waves 0-3)

    __shared__ __align__(16) float xs[2][IN_DIM];
    __shared__ unsigned long long zm7[SPIKE_STEPS][8];
    __shared__ int act[HIDDEN];
    __shared__ __align__(16) float fmp[HIDDEN][8];   // rank-indexed masks
    __shared__ float red[8];

    const float beta0 = betas[0], beta1 = betas[1], beta2 = betas[2];
    const float thr0  = thrs[0],  thr1  = thrs[1],  thr2  = thrs[2];

    // layer-0 state: neuron tid (512-wide). layers 1/2 + output state:
    // 2-col layout on mv threads (cols tid, tid+256).
    float mem0 = 0.f;
    float mem1A = 0.f, mem1B = 0.f;
    float mem2A = 0.f, mem2B = 0.f;
    float a0s = 0.f, a1s = 0.f;
    const int cA = tid & 255;
    const int cB = cA + 256;
    const float wo0A = Wout[cA];
    const float wo0B = Wout[cB];
    const float wo1A = Wout[HIDDEN + cA];
    const float wo1B = Wout[HIDDEN + cB];

    if (tid < IN_DIM) xs[0][tid] = x[(0 * BATCH + b) * IN_DIM + tid];
    __syncthreads();                                        // prologue

    for (int i = 0; i < SEQ_LEN; ++i) {
        const int cur = i & 1;

        // ---- phase 1: layer-0 matvec + 7-step recurrence -> z0 ballots ----
        float cur0 = 0.f;
        #pragma unroll 8
        for (int k = 0; k < IN_DIM; ++k)
            cur0 = __fmaf_rn(xs[cur][k], W0T[k * HIDDEN + tid], cur0);

        if (i + 1 < SEQ_LEN && tid < IN_DIM)
            xs[cur ^ 1][tid] = x[((i + 1) * BATCH + b) * IN_DIM + tid];

        int m7 = 0;
        #pragma unroll
        for (int s = 0; s < SPIKE_STEPS; ++s) {
            bool reset0 = (mem0 - thr0) > 0.f;
            mem0 = reset0 ? 0.f : __fadd_rn(__fmul_rn(beta0, mem0), cur0);
            bool z0 = (mem0 - thr0) > 0.f;
            m7 |= (int)z0 << s;
            unsigned long long bal = __ballot(z0);
            if (lane == 0) zm7[s][wid] = bal;
        }
        __syncthreads();                                    // B1: z0 ballots

        int npad = build_union(zm7, act, fmp, wid, lane, tid, m7);
        __syncthreads();                                    // B2: act/fmp v1

        // ---- phase 2: layer-1 matvec + recurrence -> z1 ballots (LDS) ----
        if (mv) {
            f32x2 accA[4] = {{0.f,0.f},{0.f,0.f},{0.f,0.f},{0.f,0.f}};
            f32x2 accB[4] = {{0.f,0.f},{0.f,0.f},{0.f,0.f},{0.f,0.f}};
            union_sum7_2(W1T, act, fmp, npad, tid, accA, accB);
            const float accsA[SPIKE_STEPS] =
                {accA[0].x, accA[0].y, accA[1].x, accA[1].y, accA[2].x, accA[2].y, accA[3].x};
            const float accsB[SPIKE_STEPS] =
                {accB[0].x, accB[0].y, accB[1].x, accB[1].y, accB[2].x, accB[2].y, accB[3].x};

            // ballots: col A = neuron tid (qwords 0-3), col B = neuron
            // tid+256 (qwords 4-7) — bit of neuron n at (n>>6, n&63).
            // Writing zm7 here is safe: all reads of the z0 ballots
            // finished before B2.
            #pragma unroll
            for (int s = 0; s < SPIKE_STEPS; ++s) {
                bool r1A = (mem1A - thr1) > 0.f;
                mem1A = r1A ? 0.f : __fadd_rn(__fmul_rn(beta1, mem1A), accsA[s]);
                bool z1A = (mem1A - thr1) > 0.f;
                bool r1B = (mem1B - thr1) > 0.f;
                mem1B = r1B ? 0.f : __fadd_rn(__fmul_rn(beta1, mem1B), accsB[s]);
                bool z1B = (mem1B - thr1) > 0.f;
                unsigned long long balA = __ballot(z1A);
                unsigned long long balB = __ballot(z1B);
                if (lane == 0) {
                    zm7[s][wid] = balA;
                    zm7[s][4 + wid] = balB;
                }
            }
        }
        __syncthreads();                                    // B3: z1 ballots

        // per-neuron m7 for layer 2 (neuron tid)
        int m7b = 0;
        #pragma unroll
        for (int s = 0; s < SPIKE_STEPS; ++s)
            m7b |= (int)((zm7[s][wid] >> lane) & 1ull) << s;

        npad = build_union(zm7, act, fmp, wid, lane, tid, m7b);
        __syncthreads();                                    // B4: act/fmp v2

        // ---- phase 3: layer-2 matvec + recurrence + output ----
        if (mv) {
            f32x2 accA[4] = {{0.f,0.f},{0.f,0.f},{0.f,0.f},{0.f,0.f}};
            f32x2 accB[4] = {{0.f,0.f},{0.f,0.f},{0.f,0.f},{0.f,0.f}};
            union_sum7_2(W2T, act, fmp, npad, tid, accA, accB);
            const float accsA[SPIKE_STEPS] =
                {accA[0].x, accA[0].y, accA[1].x, accA[1].y, accA[2].x, accA[2].y, accA[3].x};
            const float accsB[SPIKE_STEPS] =
                {accB[0].x, accB[0].y, accB[1].x, accB[1].y, accB[2].x, accB[2].y, accB[3].x};

            float w0 = 0.f, w1 = 0.f;
            #pragma unroll
            for (int s = 0; s < SPIKE_STEPS; ++s) {
                bool r2A = (mem2A - thr2) > 0.f;
                mem2A = r2A ? 0.f : __fadd_rn(__fmul_rn(beta2, mem2A), accsA[s]);
                bool z2A = (mem2A - thr2) > 0.f;
                bool r2B = (mem2B - thr2) > 0.f;
                mem2B = r2B ? 0.f : __fadd_rn(__fmul_rn(beta2, mem2B), accsB[s]);
                bool z2B = (mem2B - thr2) > 0.f;
                a0s += z2A ? wo0A : 0.f;
                a0s += z2B ? wo0B : 0.f;
                a1s += z2A ? wo1A : 0.f;
                a1s += z2B ? wo1B : 0.f;
                w0 += a0s;
                w1 += a1s;
            }

            float r0 = w0, r1 = w1;
            #pragma unroll
            for (int off = 32; off > 0; off >>= 1) {
                r0 += __shfl_down(r0, off);
                r1 += __shfl_down(r1, off);
            }
            if (lane == 0) { red[wid * 2] = r0; red[wid * 2 + 1] = r1; }
        }
        __syncthreads();                                    // B5: red ready
        if (tid == 0) {
            float s0 = 0.f, s1 = 0.f;
            #pragma unroll
            for (int q = 0; q < 4; ++q) { s0 += red[q * 2]; s1 += red[q * 2 + 1]; }
            out[(i * BATCH + b) * OUT_DIM + 0] = s0 / 7.0f;
            out[(i * BATCH + b) * OUT_DIM + 1] = s1 / 7.0f;
        }
        // next write to red is >=2 barriers away (B4 of i+1); tid0's read
        // precedes its next barrier => no extra barrier needed.
    }
}

extern "C" void kernel_launch(void* const* d_in, const int* in_sizes, int n_in,
                              void* d_out, int out_size, void* d_ws, size_t ws_size,
                              hipStream_t stream) {
    const float* x     = (const float*)d_in[0];
    const float* W0    = (const float*)d_in[1];
    const float* W1    = (const float*)d_in[2];
    const float* W2    = (const float*)d_in[3];
    const float* Wout  = (const float*)d_in[4];
    const float* betas = (const float*)d_in[5];
    const float* thrs  = (const float*)d_in[6];
    float* out = (float*)d_out;

    float* ws  = (float*)d_ws;
    float* W0T = ws + W0T_OFF;
    float* W1T = ws + W1T_OFF;
    float* W2T = ws + W2T_OFF;

    {
        int n = HIDDEN * IN_DIM;
        transpose_kernel<<<(n + 255) / 256, 256, 0, stream>>>(W0, W0T, HIDDEN, IN_DIM);
    }
    {
        int n = HIDDEN * HIDDEN;
        transpose_kernel<<<(n + 255) / 256, 256, 0, stream>>>(W1, W1T, HIDDEN, HIDDEN);
        transpose_kernel<<<(n + 255) / 256, 256, 0, stream>>>(W2, W2T, HIDDEN, HIDDEN);
    }

    snn_fused_kernel<<<BATCH, HIDDEN, 0, stream>>>(
        x, Wout, betas, thrs, W0T, W1T, W2T, out);
}

// Round 16
// 3463.975 us; speedup vs baseline: 1.3839x; 1.3839x over previous
//
#include <hip/hip_runtime.h>

#define SEQ_LEN 256
#define SPIKE_STEPS 7
#define BATCH 128
#define IN_DIM 96
#define HIDDEN 512
#define OUT_DIM 2

// d_ws layout (f32 weights):
//   W0T [96*512] | W1T [512*512] | W2T [512*512] | ctr[256] | zbuf[B][256][56]u64
#define W0T_OFF 0
#define W1T_OFF (IN_DIM * HIDDEN)
#define W2T_OFF (W1T_OFF + HIDDEN * HIDDEN)
#define CTR_BYTE_OFF ((size_t)(W2T_OFF + HIDDEN * HIDDEN) * sizeof(float))
#define ZBUF_BYTE_OFF (CTR_BYTE_OFF + 1024)

typedef float f32x4 __attribute__((ext_vector_type(4)));
typedef float f32x2 __attribute__((ext_vector_type(2)));

__global__ void transpose_kernel(const float* __restrict__ in, float* __restrict__ out,
                                 int rows, int cols) {
    int idx = blockIdx.x * blockDim.x + threadIdx.x;
    if (idx < rows * cols) {
        int r = idx / cols, c = idx - r * cols;
        out[c * rows + r] = in[idx];
    }
}

// Packed f32 fma: acc.{lo,hi} += w * m.{lo,hi}. Lowers to v_pk_fma_f32
// (VOP3P, proven R5/R7). Each half is an independent IEEE RN fma; the two
// halves are DIFFERENT steps' accumulator chains => no reordering within
// any step's sum.
__device__ __forceinline__ void pkfma(f32x2& acc, float w, f32x2 m) {
    const f32x2 wv = {w, w};
    acc = __builtin_elementwise_fma(wv, m, acc);
}

// HALF-STEP union-batched row sum: this thread computes ONE column c for
// either steps 0-3 (off=0, reads fa half of fmp) or steps 4-6 (off=4, fb
// half). R13's depth-1 pipeline: act read 16-at-a-time as int4, weights
// one group ahead. Each step's sum is wholly in one thread, union rows in
// ascending rank order; active rows add fma(1,w,acc)=RN(acc+w); inactive
// add fma(0,w,acc)=acc exactly (acc never -0). Pads are (row 0, mask 0).
// => per-step sums bit-identical to R1/R3/R7/R13.
__device__ __forceinline__ void union_sum7_half(const float* __restrict__ W,
                                                const int* __restrict__ act,
                                                const float (* __restrict__ fmp)[8],
                                                int npad, int c, int off,
                                                f32x2* __restrict__ acc) {
    if (npad <= 0) return;
    const float* Wt = W + c;
    int rows[16];
    float wc[16];
    {
        const int4* av = reinterpret_cast<const int4*>(act);
        int4 a0 = av[0], a1 = av[1], a2 = av[2], a3 = av[3];
        rows[0]=a0.x; rows[1]=a0.y; rows[2]=a0.z; rows[3]=a0.w;
        rows[4]=a1.x; rows[5]=a1.y; rows[6]=a1.z; rows[7]=a1.w;
        rows[8]=a2.x; rows[9]=a2.y; rows[10]=a2.z; rows[11]=a2.w;
        rows[12]=a3.x; rows[13]=a3.y; rows[14]=a3.z; rows[15]=a3.w;
    }
    #pragma unroll
    for (int k = 0; k < 16; ++k) wc[k] = Wt[rows[k] * HIDDEN];

    for (int n = 16; n < npad; n += 16) {
        int nrows[16];
        float wn[16];
        {
            const int4* av = reinterpret_cast<const int4*>(act + n);
            int4 a0 = av[0], a1 = av[1], a2 = av[2], a3 = av[3];
            nrows[0]=a0.x; nrows[1]=a0.y; nrows[2]=a0.z; nrows[3]=a0.w;
            nrows[4]=a1.x; nrows[5]=a1.y; nrows[6]=a1.z; nrows[7]=a1.w;
            nrows[8]=a2.x; nrows[9]=a2.y; nrows[10]=a2.z; nrows[11]=a2.w;
            nrows[12]=a3.x; nrows[13]=a3.y; nrows[14]=a3.z; nrows[15]=a3.w;
        }
        #pragma unroll
        for (int k = 0; k < 16; ++k) wn[k] = Wt[nrows[k] * HIDDEN];

        const int base = n - 16;
        #pragma unroll
        for (int k = 0; k < 16; ++k) {
            f32x4 fa = *reinterpret_cast<const f32x4*>(&fmp[base + k][off]);
            pkfma(acc[0], wc[k], __builtin_shufflevector(fa, fa, 0, 1));
            pkfma(acc[1], wc[k], __builtin_shufflevector(fa, fa, 2, 3));
        }
        #pragma unroll
        for (int k = 0; k < 16; ++k) wc[k] = wn[k];
    }
    const int base = npad - 16;
    #pragma unroll
    for (int k = 0; k < 16; ++k) {
        f32x4 fa = *reinterpret_cast<const f32x4*>(&fmp[base + k][off]);
        pkfma(acc[0], wc[k], __builtin_shufflevector(fa, fa, 0, 1));
        pkfma(acc[1], wc[k], __builtin_shufflevector(fa, fa, 2, 3));
    }
}

// Build the union active list (ascending neuron order) + rank-indexed
// per-row step-mask floats (fa = steps 0-3, fb = steps 4-6 + pad).
// Full 512-thread phase (unchanged from R7/R13).
__device__ __forceinline__ int build_union(const unsigned long long (*zm7)[8],
                                           int* act, float (*fmp)[8],
                                           int wid, int lane, int tid, int m7) {
    unsigned long long um[8];
    #pragma unroll
    for (int q = 0; q < 8; ++q) {
        unsigned long long u = zm7[0][q];
        #pragma unroll
        for (int s = 1; s < SPIKE_STEPS; ++s) u |= zm7[s][q];
        um[q] = u;
    }
    int pre = 0, total = 0;
    #pragma unroll
    for (int q = 0; q < 8; ++q) {
        int p = __popcll(um[q]);
        total += p;
        if (q < wid) pre += p;
    }
    if (m7 != 0) {
        int rank = pre + __popcll(um[wid] & ((1ull << lane) - 1ull));
        act[rank] = tid;
        f32x4 v0, v4;
        #pragma unroll
        for (int s = 0; s < 4; ++s) v0[s] = ((m7 >> s) & 1) ? 1.0f : 0.0f;
        #pragma unroll
        for (int s = 0; s < 3; ++s) v4[s] = ((m7 >> (4 + s)) & 1) ? 1.0f : 0.0f;
        v4[3] = 0.f;
        *reinterpret_cast<f32x4*>(&fmp[rank][0]) = v0;
        *reinterpret_cast<f32x4*>(&fmp[rank][4]) = v4;
    }
    int npad = (total + 15) & ~15;
    if (tid < npad - total) {
        act[total + tid] = 0;                          // row 0, mask 0 pad
        const f32x4 z = {0.f, 0.f, 0.f, 0.f};
        *reinterpret_cast<f32x4*>(&fmp[total + tid][0]) = z;
        *reinterpret_cast<f32x4*>(&fmp[total + tid][4]) = z;
    }
    return npad;
}

// 4-BLOCK column-split pipeline: per batch element, blocks (sub=0,1) are
// producer halves (L0 duplicated + L1 cols [256h,256h+256)), blocks
// (sub=2,3) are consumer halves (L2 cols + output partial).
// Rationale: R7-R15 show the 2-block pipeline is LATENCY-bound at 2
// waves/SIMD (60% of issue slots empty, no resource saturated; R15's
// fusion measured matvec=13k/L0=5k/handoff=4k cyc). 512 blocks = 2
// blocks/CU = 4 waves/SIMD doubles latency-hiding TLP, and the step-split
// matvec (steps 0-3 / 4-6 per thread pair) halves each thread's
// dependency chain while keeping every step's sum in one thread =>
// pre-spike math bit-identical to R13. Output: two halves atomicAdd into
// memset-0 out (2 commutative adds => deterministic; post-spike linear
// reassociation only, R1 precedent).
__launch_bounds__(512, 4)
__global__ void snn_pipe4_kernel(const float* __restrict__ x,     // [256,128,96]
                                 const float* __restrict__ Wout,  // [2,512]
                                 const float* __restrict__ betas, // [3]
                                 const float* __restrict__ thrs,  // [3]
                                 const float* __restrict__ W0T,   // [96,512]
                                 const float* __restrict__ W1T,   // [512,512]
                                 const float* __restrict__ W2T,   // [512,512]
                                 unsigned long long* __restrict__ zbuf,
                                 int* __restrict__ ctr,
                                 float* __restrict__ out)         // [256,128,2]
{
    const int b    = blockIdx.x >> 2;
    const int sub  = blockIdx.x & 3;
    const int role = sub >> 1;          // 0 = producer, 1 = consumer
    const int h    = sub & 1;           // column half
    const int tid  = threadIdx.x;
    const int lane = tid & 63;
    const int wid  = tid >> 6;
    const int tcol = tid & 255;
    const int c    = h * 256 + tcol;    // owned column
    const bool lo  = (tid < 256);       // step-split: lo=steps0-3, hi=4-6

    __shared__ __align__(16) float xs[2][IN_DIM];
    __shared__ unsigned long long zm7[SPIKE_STEPS][8];
    __shared__ int act[HIDDEN];
    __shared__ __align__(16) float fmp[HIDDEN][8];
    __shared__ float axch[256][4];      // partner accs (steps 4-6)
    __shared__ float red[8];

    if (role == 0) {
        // ---------------- producer half: L0 (full) + L1 (cols of h) ------
        const float beta0 = betas[0], beta1 = betas[1];
        const float thr0  = thrs[0],  thr1  = thrs[1];
        float mem0 = 0.f;               // neuron tid (full 512, duplicated)
        float mem1 = 0.f;               // col c (lo threads only)
        unsigned long long* zb = zbuf + (size_t)b * SEQ_LEN * 56;

        if (tid < IN_DIM) xs[0][tid] = x[(0 * BATCH + b) * IN_DIM + tid];
        __syncthreads();                                    // prologue

        for (int i = 0; i < SEQ_LEN; ++i) {
            const int cur = i & 1;

            float cur0 = 0.f;
            #pragma unroll 8
            for (int k = 0; k < IN_DIM; ++k)
                cur0 = __fmaf_rn(xs[cur][k], W0T[k * HIDDEN + tid], cur0);

            if (i + 1 < SEQ_LEN && tid < IN_DIM)
                xs[cur ^ 1][tid] = x[((i + 1) * BATCH + b) * IN_DIM + tid];

            int m7 = 0;
            #pragma unroll
            for (int s = 0; s < SPIKE_STEPS; ++s) {
                bool reset0 = (mem0 - thr0) > 0.f;
                mem0 = reset0 ? 0.f : __fadd_rn(__fmul_rn(beta0, mem0), cur0);
                bool z0 = (mem0 - thr0) > 0.f;
                m7 |= (int)z0 << s;
                unsigned long long bal = __ballot(z0);
                if (lane == 0) zm7[s][wid] = bal;
            }
            __syncthreads();                                // B1: z0 ballots

            int npad = build_union(zm7, act, fmp, wid, lane, tid, m7);
            __syncthreads();                                // B2: act/fmp

            f32x2 acc[2] = {{0.f, 0.f}, {0.f, 0.f}};
            union_sum7_half(W1T, act, fmp, npad, c, lo ? 0 : 4, acc);
            if (!lo) {
                axch[tcol][0] = acc[0].x;   // step 4
                axch[tcol][1] = acc[0].y;   // step 5
                axch[tcol][2] = acc[1].x;   // step 6
            }
            __syncthreads();                                // B3: axch ready

            if (lo) {
                const float accs[SPIKE_STEPS] =
                    {acc[0].x, acc[0].y, acc[1].x, acc[1].y,
                     axch[tcol][0], axch[tcol][1], axch[tcol][2]};
                #pragma unroll
                for (int s = 0; s < SPIKE_STEPS; ++s) {
                    bool r1 = (mem1 - thr1) > 0.f;
                    mem1 = r1 ? 0.f : __fadd_rn(__fmul_rn(beta1, mem1), accs[s]);
                    bool z1 = (mem1 - thr1) > 0.f;
                    unsigned long long bal1 = __ballot(z1);
                    if (lane == 0)
                        __hip_atomic_store(&zb[(size_t)i * 56 + s * 8 + 4 * h + wid],
                                           bal1, __ATOMIC_RELAXED,
                                           __HIP_MEMORY_SCOPE_AGENT);
                }
            }
            __syncthreads();   // B4: mask stores drained (vmcnt 0)
            if (tid == 0)
                __hip_atomic_store(&ctr[2 * b + h], i + 1,
                                   __ATOMIC_RELAXED, __HIP_MEMORY_SCOPE_AGENT);
        }
    } else {
        // ---------------- consumer half: L2 (cols of h) + output ---------
        const float beta2 = betas[2];
        const float thr2  = thrs[2];
        const float wo0c = Wout[c];
        const float wo1c = Wout[HIDDEN + c];
        float mem2 = 0.f, a0s = 0.f, a1s = 0.f;    // lo threads only
        const unsigned long long* zb = zbuf + (size_t)b * SEQ_LEN * 56;

        for (int i = 0; i < SEQ_LEN; ++i) {
            if (tid < 56) {
                while (__hip_atomic_load(&ctr[2 * b], __ATOMIC_RELAXED,
                                         __HIP_MEMORY_SCOPE_AGENT) < i + 1 ||
                       __hip_atomic_load(&ctr[2 * b + 1], __ATOMIC_RELAXED,
                                         __HIP_MEMORY_SCOPE_AGENT) < i + 1)
                    __builtin_amdgcn_s_sleep(1);
                ((unsigned long long*)zm7)[tid] =
                    __hip_atomic_load(&zb[(size_t)i * 56 + tid],
                                      __ATOMIC_RELAXED, __HIP_MEMORY_SCOPE_AGENT);
            }
            __syncthreads();                                // B1: zm7 ready

            int m7b = 0;
            #pragma unroll
            for (int s = 0; s < SPIKE_STEPS; ++s)
                m7b |= (int)((zm7[s][wid] >> lane) & 1ull) << s;

            int npad = build_union(zm7, act, fmp, wid, lane, tid, m7b);
            __syncthreads();                                // B2: act/fmp

            f32x2 acc[2] = {{0.f, 0.f}, {0.f, 0.f}};
            union_sum7_half(W2T, act, fmp, npad, c, lo ? 0 : 4, acc);
            if (!lo) {
                axch[tcol][0] = acc[0].x;
                axch[tcol][1] = acc[0].y;
                axch[tcol][2] = acc[1].x;
            }
            __syncthreads();                                // B3: axch ready

            if (lo) {
                const float accs[SPIKE_STEPS] =
                    {acc[0].x, acc[0].y, acc[1].x, acc[1].y,
                     axch[tcol][0], axch[tcol][1], axch[tcol][2]};
                float w0 = 0.f, w1 = 0.f;
                #pragma unroll
                for (int s = 0; s < SPIKE_STEPS; ++s) {
                    bool r2 = (mem2 - thr2) > 0.f;
                    mem2 = r2 ? 0.f : __fadd_rn(__fmul_rn(beta2, mem2), accs[s]);
                    bool z2 = (mem2 - thr2) > 0.f;
                    a0s += z2 ? wo0c : 0.f;
                    a1s += z2 ? wo1c : 0.f;
                    w0 += a0s;
                    w1 += a1s;
                }
                float r0 = w0, r1 = w1;
                #pragma unroll
                for (int off = 32; off > 0; off >>= 1) {
                    r0 += __shfl_down(r0, off);
                    r1 += __shfl_down(r1, off);
                }
                if (lane == 0) { red[wid * 2] = r0; red[wid * 2 + 1] = r1; }
            }
            __syncthreads();                                // B4: red ready
            if (tid == 0) {
                float s0 = 0.f, s1 = 0.f;
                #pragma unroll
                for (int q = 0; q < 4; ++q) { s0 += red[q * 2]; s1 += red[q * 2 + 1]; }
                // two halves contribute; atomicAdd into memset-0 out is
                // deterministic for 2 commutative adds.
                atomicAdd(&out[(i * BATCH + b) * OUT_DIM + 0], s0 / 7.0f);
                atomicAdd(&out[(i * BATCH + b) * OUT_DIM + 1], s1 / 7.0f);
            }
        }
    }
}

extern "C" void kernel_launch(void* const* d_in, const int* in_sizes, int n_in,
                              void* d_out, int out_size, void* d_ws, size_t ws_size,
                              hipStream_t stream) {
    const float* x     = (const float*)d_in[0];
    const float* W0    = (const float*)d_in[1];
    const float* W1    = (const float*)d_in[2];
    const float* W2    = (const float*)d_in[3];
    const float* Wout  = (const float*)d_in[4];
    const float* betas = (const float*)d_in[5];
    const float* thrs  = (const float*)d_in[6];
    float* out = (float*)d_out;

    float* ws  = (float*)d_ws;
    float* W0T = ws + W0T_OFF;
    float* W1T = ws + W1T_OFF;
    float* W2T = ws + W2T_OFF;
    int* ctr = (int*)((char*)d_ws + CTR_BYTE_OFF);
    unsigned long long* zbuf = (unsigned long long*)((char*)d_ws + ZBUF_BYTE_OFF);

    {
        int n = HIDDEN * IN_DIM;
        transpose_kernel<<<(n + 255) / 256, 256, 0, stream>>>(W0, W0T, HIDDEN, IN_DIM);
    }
    {
        int n = HIDDEN * HIDDEN;
        transpose_kernel<<<(n + 255) / 256, 256, 0, stream>>>(W1, W1T, HIDDEN, HIDDEN);
        transpose_kernel<<<(n + 255) / 256, 256, 0, stream>>>(W2, W2T, HIDDEN, HIDDEN);
    }

    hipMemsetAsync((char*)d_ws + CTR_BYTE_OFF, 0, 1024, stream);

    snn_pipe4_kernel<<<4 * BATCH, HIDDEN, 0, stream>>>(
        x, Wout, betas, thrs, W0T, W1T, W2T, zbuf, ctr, out);
}

// Round 17
// 2747.066 us; speedup vs baseline: 1.7451x; 1.2610x over previous
//
#include <hip/hip_runtime.h>

#define SEQ_LEN 256
#define SPIKE_STEPS 7
#define BATCH 128
#define IN_DIM 96
#define HIDDEN 512
#define OUT_DIM 2

// d_ws layout (f32 weights, R13 order):
//   W0T [96*512] | W1Tp [512*512] | W2Tp [512*512] | ctr | zbuf[B][256][56]u64
// W1Tp/W2Tp: transposed with neuron->physical column pairing
//   p(n) = (n<256) ? 2n : 2(n-256)+1
// so one float2 at (2t,2t+1) holds neurons (t, t+256) — exactly R13's
// column ownership; weight VALUES and per-step summation order unchanged.
#define W0T_OFF 0
#define W1T_OFF (IN_DIM * HIDDEN)
#define W2T_OFF (W1T_OFF + HIDDEN * HIDDEN)
#define CTR_BYTE_OFF ((size_t)(W2T_OFF + HIDDEN * HIDDEN) * sizeof(float))
#define ZBUF_BYTE_OFF (CTR_BYTE_OFF + 1024)

typedef float f32x4 __attribute__((ext_vector_type(4)));
typedef float f32x2 __attribute__((ext_vector_type(2)));

__global__ void transpose_kernel(const float* __restrict__ in, float* __restrict__ out,
                                 int rows, int cols) {
    int idx = blockIdx.x * blockDim.x + threadIdx.x;
    if (idx < rows * cols) {
        int r = idx / cols, c = idx - r * cols;
        out[c * rows + r] = in[idx];
    }
}

// Transpose with neuron->physical column pairing (values untouched).
__global__ void transpose_perm_kernel(const float* __restrict__ in,   // [512][512] (neuron, input)
                                      float* __restrict__ out) {      // [input][physical col]
    int idx = blockIdx.x * blockDim.x + threadIdx.x;
    if (idx < HIDDEN * HIDDEN) {
        int n = idx / HIDDEN, i = idx - n * HIDDEN;
        int p = (n < 256) ? (2 * n) : (2 * (n - 256) + 1);
        out[i * HIDDEN + p] = in[n * HIDDEN + i];
    }
}

// Packed f32 fma: acc.{lo,hi} += w * m.{lo,hi}. Lowers to v_pk_fma_f32
// (VOP3P, proven R5/R7). Each half is an independent IEEE RN fma; the two
// halves are DIFFERENT steps' accumulator chains => no reordering within
// any step's sum.
__device__ __forceinline__ void pkfma(f32x2& acc, float w, f32x2 m) {
    const f32x2 wv = {w, w};
    acc = __builtin_elementwise_fma(wv, m, acc);
}

// TWO-COLUMN union-batched 7-step row sum, float2 weight loads.
// Clean re-test of the VMEM-instruction-rate theory: the 2900us plateau
// variants (R7/R9/R13) all issue 8 wave-VMEM instrs per union row; this
// halves it to 4 (one dwordx2 per thread per row covering both owned
// columns) with all R14 confounds removed.
// Numerics: identical values and per-step ascending-rank order as R13
// (pairing is a storage permutation only; R14 passed with absmax 0.25).
__device__ __forceinline__ void union_sum7_2(const float* __restrict__ W,
                                             const int* __restrict__ act,
                                             const float (* __restrict__ fmp)[8],
                                             int npad, int tid,
                                             f32x2* __restrict__ accA,
                                             f32x2* __restrict__ accB) {
    if (npad <= 0) return;
    const float2* Wt2 = reinterpret_cast<const float2*>(W) + tid;  // row stride 256 float2
    int rows[16];
    float wcA[16], wcB[16];
    {
        const int4* av = reinterpret_cast<const int4*>(act);
        int4 a0 = av[0], a1 = av[1], a2 = av[2], a3 = av[3];
        rows[0]=a0.x; rows[1]=a0.y; rows[2]=a0.z; rows[3]=a0.w;
        rows[4]=a1.x; rows[5]=a1.y; rows[6]=a1.z; rows[7]=a1.w;
        rows[8]=a2.x; rows[9]=a2.y; rows[10]=a2.z; rows[11]=a2.w;
        rows[12]=a3.x; rows[13]=a3.y; rows[14]=a3.z; rows[15]=a3.w;
    }
    #pragma unroll
    for (int k = 0; k < 16; ++k) {
        float2 v = Wt2[rows[k] * 256];
        wcA[k] = v.x; wcB[k] = v.y;
    }

    for (int n = 16; n < npad; n += 16) {
        int nrows[16];
        float wnA[16], wnB[16];
        {
            const int4* av = reinterpret_cast<const int4*>(act + n);
            int4 a0 = av[0], a1 = av[1], a2 = av[2], a3 = av[3];
            nrows[0]=a0.x; nrows[1]=a0.y; nrows[2]=a0.z; nrows[3]=a0.w;
            nrows[4]=a1.x; nrows[5]=a1.y; nrows[6]=a1.z; nrows[7]=a1.w;
            nrows[8]=a2.x; nrows[9]=a2.y; nrows[10]=a2.z; nrows[11]=a2.w;
            nrows[12]=a3.x; nrows[13]=a3.y; nrows[14]=a3.z; nrows[15]=a3.w;
        }
        #pragma unroll
        for (int k = 0; k < 16; ++k) {
            float2 v = Wt2[nrows[k] * 256];
            wnA[k] = v.x; wnB[k] = v.y;
        }

        const int base = n - 16;
        #pragma unroll
        for (int k = 0; k < 16; ++k) {
            f32x4 fa = *reinterpret_cast<const f32x4*>(&fmp[base + k][0]);
            f32x4 fb = *reinterpret_cast<const f32x4*>(&fmp[base + k][4]);
            f32x2 m01 = __builtin_shufflevector(fa, fa, 0, 1);
            f32x2 m23 = __builtin_shufflevector(fa, fa, 2, 3);
            f32x2 m45 = __builtin_shufflevector(fb, fb, 0, 1);
            f32x2 m67 = __builtin_shufflevector(fb, fb, 2, 3);
            pkfma(accA[0], wcA[k], m01);
            pkfma(accA[1], wcA[k], m23);
            pkfma(accA[2], wcA[k], m45);
            pkfma(accA[3], wcA[k], m67);
            pkfma(accB[0], wcB[k], m01);
            pkfma(accB[1], wcB[k], m23);
            pkfma(accB[2], wcB[k], m45);
            pkfma(accB[3], wcB[k], m67);
        }
        #pragma unroll
        for (int k = 0; k < 16; ++k) { wcA[k] = wnA[k]; wcB[k] = wnB[k]; }
    }
    const int base = npad - 16;
    #pragma unroll
    for (int k = 0; k < 16; ++k) {
        f32x4 fa = *reinterpret_cast<const f32x4*>(&fmp[base + k][0]);
        f32x4 fb = *reinterpret_cast<const f32x4*>(&fmp[base + k][4]);
        f32x2 m01 = __builtin_shufflevector(fa, fa, 0, 1);
        f32x2 m23 = __builtin_shufflevector(fa, fa, 2, 3);
        f32x2 m45 = __builtin_shufflevector(fb, fb, 0, 1);
        f32x2 m67 = __builtin_shufflevector(fb, fb, 2, 3);
        pkfma(accA[0], wcA[k], m01);
        pkfma(accA[1], wcA[k], m23);
        pkfma(accA[2], wcA[k], m45);
        pkfma(accA[3], wcA[k], m67);
        pkfma(accB[0], wcB[k], m01);
        pkfma(accB[1], wcB[k], m23);
        pkfma(accB[2], wcB[k], m45);
        pkfma(accB[3], wcB[k], m67);
    }
}

// Build the union active list (ascending neuron order) + rank-indexed
// per-row step-mask floats. Full 512-thread phase (unchanged from R7/R13).
__device__ __forceinline__ int build_union(const unsigned long long (*zm7)[8],
                                           int* act, float (*fmp)[8],
                                           int wid, int lane, int tid, int m7) {
    unsigned long long um[8];
    #pragma unroll
    for (int q = 0; q < 8; ++q) {
        unsigned long long u = zm7[0][q];
        #pragma unroll
        for (int s = 1; s < SPIKE_STEPS; ++s) u |= zm7[s][q];
        um[q] = u;
    }
    int pre = 0, total = 0;
    #pragma unroll
    for (int q = 0; q < 8; ++q) {
        int p = __popcll(um[q]);
        total += p;
        if (q < wid) pre += p;
    }
    if (m7 != 0) {
        int rank = pre + __popcll(um[wid] & ((1ull << lane) - 1ull));
        act[rank] = tid;
        f32x4 v0, v4;
        #pragma unroll
        for (int s = 0; s < 4; ++s) v0[s] = ((m7 >> s) & 1) ? 1.0f : 0.0f;
        #pragma unroll
        for (int s = 0; s < 3; ++s) v4[s] = ((m7 >> (4 + s)) & 1) ? 1.0f : 0.0f;
        v4[3] = 0.f;
        *reinterpret_cast<f32x4*>(&fmp[rank][0]) = v0;
        *reinterpret_cast<f32x4*>(&fmp[rank][4]) = v4;
    }
    int npad = (total + 15) & ~15;
    if (tid < npad - total) {
        act[total + tid] = 0;                          // row 0, mask 0 pad
        const f32x4 z = {0.f, 0.f, 0.f, 0.f};
        *reinterpret_cast<f32x4*>(&fmp[total + tid][0]) = z;
        *reinterpret_cast<f32x4*>(&fmp[total + tid][4]) = z;
    }
    return npad;
}

// Two-stage pipeline: even blocks = producer (layer0+layer1), odd = consumer
// (layer2+output). R13 structure throughout; only the matvec weight loads
// changed to float2 (paired layout).
__launch_bounds__(512, 1)
__global__ void snn_pipe_kernel(const float* __restrict__ x,     // [256,128,96]
                                const float* __restrict__ Wout,  // [2,512]
                                const float* __restrict__ betas, // [3]
                                const float* __restrict__ thrs,  // [3]
                                const float* __restrict__ W0T,   // [96,512]
                                const float* __restrict__ W1T,   // [512,512] paired
                                const float* __restrict__ W2T,   // [512,512] paired
                                unsigned long long* __restrict__ zbuf,
                                int* __restrict__ ctr,
                                float* __restrict__ out)         // [256,128,2]
{
    const int b    = blockIdx.x >> 1;
    const int role = blockIdx.x & 1;
    const int tid  = threadIdx.x;
    const int lane = tid & 63;
    const int wid  = tid >> 6;
    const bool mv  = (tid < 256);       // matvec-active threads (waves 0-3)

    __shared__ __align__(16) float xs[2][IN_DIM];
    __shared__ unsigned long long zm7[SPIKE_STEPS][8];
    __shared__ int act[HIDDEN];
    __shared__ __align__(16) float fmp[HIDDEN][8];   // rank-indexed masks
    __shared__ float red[8];

    if (role == 0) {
        // ---------------- producer: layer0 + layer1 ----------------
        const float beta0 = betas[0], beta1 = betas[1];
        const float thr0  = thrs[0],  thr1  = thrs[1];
        float mem0 = 0.f;                       // 512-layout: neuron tid
        float mem1A = 0.f, mem1B = 0.f;         // 2-col: neurons tid, tid+256
        unsigned long long* zb = zbuf + (size_t)b * SEQ_LEN * 56;

        if (tid < IN_DIM) xs[0][tid] = x[(0 * BATCH + b) * IN_DIM + tid];
        __syncthreads();                                        // prologue

        for (int i = 0; i < SEQ_LEN; ++i) {
            const int cur = i & 1;

            float cur0 = 0.f;
            #pragma unroll 8
            for (int k = 0; k < IN_DIM; ++k)
                cur0 = __fmaf_rn(xs[cur][k], W0T[k * HIDDEN + tid], cur0);

            // prefetch next step's x slice into the other xs buffer
            if (i + 1 < SEQ_LEN && tid < IN_DIM)
                xs[cur ^ 1][tid] = x[((i + 1) * BATCH + b) * IN_DIM + tid];

            // layer-0 recurrence (autonomous within the seq step), 512-wide
            int m7 = 0;
            #pragma unroll
            for (int s = 0; s < SPIKE_STEPS; ++s) {
                bool reset0 = (mem0 - thr0) > 0.f;
                mem0 = reset0 ? 0.f : __fadd_rn(__fmul_rn(beta0, mem0), cur0);
                bool z0 = (mem0 - thr0) > 0.f;
                m7 |= (int)z0 << s;
                unsigned long long bal = __ballot(z0);
                if (lane == 0) zm7[s][wid] = bal;
            }
            __syncthreads();                                    // B1: zm7 ready

            int npad = build_union(zm7, act, fmp, wid, lane, tid, m7);
            __syncthreads();                                    // B2: act/fmp ready

            if (mv) {
                f32x2 accA[4] = {{0.f,0.f},{0.f,0.f},{0.f,0.f},{0.f,0.f}};
                f32x2 accB[4] = {{0.f,0.f},{0.f,0.f},{0.f,0.f},{0.f,0.f}};
                union_sum7_2(W1T, act, fmp, npad, tid, accA, accB);
                const float accsA[SPIKE_STEPS] =
                    {accA[0].x, accA[0].y, accA[1].x, accA[1].y, accA[2].x, accA[2].y, accA[3].x};
                const float accsB[SPIKE_STEPS] =
                    {accB[0].x, accB[0].y, accB[1].x, accB[1].y, accB[2].x, accB[2].y, accB[3].x};

                // layer-1 recurrence for both columns; ballots standard
                // layout: col A = neuron tid (qwords 0-3), col B = neuron
                // tid+256 (qwords 4-7) — bit of neuron n at (n>>6, n&63).
                #pragma unroll
                for (int s = 0; s < SPIKE_STEPS; ++s) {
                    bool r1A = (mem1A - thr1) > 0.f;
                    mem1A = r1A ? 0.f : __fadd_rn(__fmul_rn(beta1, mem1A), accsA[s]);
                    bool z1A = (mem1A - thr1) > 0.f;
                    bool r1B = (mem1B - thr1) > 0.f;
                    mem1B = r1B ? 0.f : __fadd_rn(__fmul_rn(beta1, mem1B), accsB[s]);
                    bool z1B = (mem1B - thr1) > 0.f;
                    unsigned long long balA = __ballot(z1A);
                    unsigned long long balB = __ballot(z1B);
                    if (lane == 0) {
                        __hip_atomic_store(&zb[(size_t)i * 56 + s * 8 + wid], balA,
                                           __ATOMIC_RELAXED, __HIP_MEMORY_SCOPE_AGENT);
                        __hip_atomic_store(&zb[(size_t)i * 56 + s * 8 + 4 + wid], balB,
                                           __ATOMIC_RELAXED, __HIP_MEMORY_SCOPE_AGENT);
                    }
                }
            }
            __syncthreads();   // B3: all waves' mask stores drained (vmcnt 0)
            if (tid == 0)
                __hip_atomic_store(&ctr[b], i + 1,
                                   __ATOMIC_RELAXED, __HIP_MEMORY_SCOPE_AGENT);
        }
    } else {
        // ---------------- consumer: layer2 + output ----------------
        const float beta2 = betas[2];
        const float thr2  = thrs[2];
        const int cA = tid & 255;
        const int cB = cA + 256;
        const float wo0A = Wout[cA];
        const float wo0B = Wout[cB];
        const float wo1A = Wout[HIDDEN + cA];
        const float wo1B = Wout[HIDDEN + cB];
        float mem2A = 0.f, mem2B = 0.f;
        float a0s = 0.f, a1s = 0.f;            // combined over both columns
        const unsigned long long* zb = zbuf + (size_t)b * SEQ_LEN * 56;

        for (int i = 0; i < SEQ_LEN; ++i) {
            // merged spin + mask load (wave 0 only), one barrier total.
            if (tid < 56) {
                while (__hip_atomic_load(&ctr[b], __ATOMIC_RELAXED,
                                         __HIP_MEMORY_SCOPE_AGENT) < i + 1)
                    __builtin_amdgcn_s_sleep(1);
                ((unsigned long long*)zm7)[tid] =
                    __hip_atomic_load(&zb[(size_t)i * 56 + tid],
                                      __ATOMIC_RELAXED, __HIP_MEMORY_SCOPE_AGENT);
            }
            __syncthreads();                                    // B1: zm7 ready

            // per-neuron m7 (standard layout: neuron tid)
            int m7 = 0;
            #pragma unroll
            for (int s = 0; s < SPIKE_STEPS; ++s)
                m7 |= (int)((zm7[s][wid] >> lane) & 1ull) << s;

            int npad = build_union(zm7, act, fmp, wid, lane, tid, m7);
            __syncthreads();                                    // B2: act/fmp ready

            if (mv) {
                f32x2 accA[4] = {{0.f,0.f},{0.f,0.f},{0.f,0.f},{0.f,0.f}};
                f32x2 accB[4] = {{0.f,0.f},{0.f,0.f},{0.f,0.f},{0.f,0.f}};
                union_sum7_2(W2T, act, fmp, npad, tid, accA, accB);
                const float accsA[SPIKE_STEPS] =
                    {accA[0].x, accA[0].y, accA[1].x, accA[1].y, accA[2].x, accA[2].y, accA[3].x};
                const float accsB[SPIKE_STEPS] =
                    {accB[0].x, accB[0].y, accB[1].x, accB[1].y, accB[2].x, accB[2].y, accB[3].x};

                float w0 = 0.f, w1 = 0.f;
                #pragma unroll
                for (int s = 0; s < SPIKE_STEPS; ++s) {
                    bool r2A = (mem2A - thr2) > 0.f;
                    mem2A = r2A ? 0.f : __fadd_rn(__fmul_rn(beta2, mem2A), accsA[s]);
                    bool z2A = (mem2A - thr2) > 0.f;
                    bool r2B = (mem2B - thr2) > 0.f;
                    mem2B = r2B ? 0.f : __fadd_rn(__fmul_rn(beta2, mem2B), accsB[s]);
                    bool z2B = (mem2B - thr2) > 0.f;
                    a0s += z2A ? wo0A : 0.f;
                    a0s += z2B ? wo0B : 0.f;
                    a1s += z2A ? wo1A : 0.f;
                    a1s += z2B ? wo1B : 0.f;
                    w0 += a0s;
                    w1 += a1s;
                }

                // cross-thread reduction over the 4 active waves
                float r0 = w0, r1 = w1;
                #pragma unroll
                for (int off = 32; off > 0; off >>= 1) {
                    r0 += __shfl_down(r0, off);
                    r1 += __shfl_down(r1, off);
                }
                if (lane == 0) { red[wid * 2] = r0; red[wid * 2 + 1] = r1; }
            }
            __syncthreads();                                    // B3
            if (tid == 0) {
                float s0 = 0.f, s1 = 0.f;
                #pragma unroll
                for (int q = 0; q < 4; ++q) { s0 += red[q * 2]; s1 += red[q * 2 + 1]; }
                out[(i * BATCH + b) * OUT_DIM + 0] = s0 / 7.0f;
                out[(i * BATCH + b) * OUT_DIM + 1] = s1 / 7.0f;
            }
            // next write to red is a full seq step away (>=2 barriers) and
            // tid0's read precedes its next barrier => no extra barrier.
        }
    }
}

extern "C" void kernel_launch(void* const* d_in, const int* in_sizes, int n_in,
                              void* d_out, int out_size, void* d_ws, size_t ws_size,
                              hipStream_t stream) {
    const float* x     = (const float*)d_in[0];
    const float* W0    = (const float*)d_in[1];
    const float* W1    = (const float*)d_in[2];
    const float* W2    = (const float*)d_in[3];
    const float* Wout  = (const float*)d_in[4];
    const float* betas = (const float*)d_in[5];
    const float* thrs  = (const float*)d_in[6];
    float* out = (float*)d_out;

    float* ws  = (float*)d_ws;
    float* W0T = ws + W0T_OFF;
    float* W1T = ws + W1T_OFF;
    float* W2T = ws + W2T_OFF;
    int* ctr = (int*)((char*)d_ws + CTR_BYTE_OFF);
    unsigned long long* zbuf = (unsigned long long*)((char*)d_ws + ZBUF_BYTE_OFF);

    {
        int n = HIDDEN * IN_DIM;
        transpose_kernel<<<(n + 255) / 256, 256, 0, stream>>>(W0, W0T, HIDDEN, IN_DIM);
    }
    {
        int n = HIDDEN * HIDDEN;
        transpose_perm_kernel<<<(n + 255) / 256, 256, 0, stream>>>(W1, W1T);
        transpose_perm_kernel<<<(n + 255) / 256, 256, 0, stream>>>(W2, W2T);
    }

    hipMemsetAsync((char*)d_ws + CTR_BYTE_OFF, 0, 1024, stream);

    snn_pipe_kernel<<<2 * BATCH, HIDDEN, 0, stream>>>(
        x, Wout, betas, thrs, W0T, W1T, W2T, zbuf, ctr, out);
}